// Round 1
// baseline (298.143 us; speedup 1.0000x reference)
//
#include <hip/hip_runtime.h>
#include <cstdint>

#define S_DIM 4096
#define E_DIM 1024
#define D_DIM 1024

typedef __bf16 bf16x8 __attribute__((ext_vector_type(8)));
typedef float  f32x4  __attribute__((ext_vector_type(4)));
typedef unsigned short u16x8 __attribute__((ext_vector_type(8)));

__device__ __forceinline__ unsigned short f2bf(float f) {
  unsigned u = __float_as_uint(f);
  unsigned r = (u + 0x7fffu + ((u >> 16) & 1u)) >> 16;   // RNE
  return (unsigned short)r;
}
__device__ __forceinline__ float bf2f(unsigned short b) {
  return __uint_as_float(((unsigned)b) << 16);
}
__device__ __forceinline__ unsigned short to_bf16_bits(float f) { return f2bf(f); }
__device__ __forceinline__ unsigned short to_bf16_bits(unsigned short s) { return s; }

// ---------------- elementwise f32 -> bf16 ----------------
__global__ __launch_bounds__(256) void cvt_f32_bf16_kernel(
    const float* __restrict__ in, unsigned short* __restrict__ out, int n) {
  int i = (blockIdx.x * 256 + threadIdx.x) * 8;
  if (i >= n) return;
  float4 a = *(const float4*)(in + i);
  float4 b = *(const float4*)(in + i + 4);
  u16x8 o;
  o[0] = f2bf(a.x); o[1] = f2bf(a.y); o[2] = f2bf(a.z); o[3] = f2bf(a.w);
  o[4] = f2bf(b.x); o[5] = f2bf(b.y); o[6] = f2bf(b.z); o[7] = f2bf(b.w);
  *(u16x8*)(out + i) = o;
}

// ---------------- tiled transpose -> bf16: out[C][R] = in[R][C] ----------------
template <typename TIN>
__global__ __launch_bounds__(256) void transpose_to_bf16_kernel(
    const TIN* __restrict__ in, unsigned short* __restrict__ out, int R, int C) {
  __shared__ unsigned short tile[32][33];           // +1 pad breaks bank conflicts
  int bc = blockIdx.x * 32, br = blockIdx.y * 32;
  int tx = threadIdx.x & 31;
  int ty = threadIdx.x >> 5;                        // 0..7
#pragma unroll
  for (int i = 0; i < 32; i += 8)
    tile[ty + i][tx] = to_bf16_bits(in[(size_t)(br + ty + i) * C + bc + tx]);
  __syncthreads();
#pragma unroll
  for (int i = 0; i < 32; i += 8)
    out[(size_t)(bc + ty + i) * R + br + tx] = tile[tx][ty + i];
}

// ---------------- bf16 GEMM: C[M][N] = scale * A[M][K] @ Bt[N][K]^T ----------------
// 128x128 tile, BK=32, 4 waves (2x2), each wave 64x64 via 4x4 MFMA 16x16x32 tiles.
// Verified layouts (learn_hip m89/m91/m92): A-frag lane l -> A[m=l&15][k=(l>>4)*8+j];
// B-frag lane l -> B[k=(l>>4)*8+j][n=l&15] (load Bt[n][k] contiguous);
// C/D lane l reg r -> D[row=(l>>4)*4+r][col=l&15].
#define BM 128
#define BN 128
#define BK 32

template <bool OUT_BF16>
__global__ __launch_bounds__(256, 2) void gemm_bt_kernel(
    const unsigned short* __restrict__ A,    // [M][K] bf16 bits
    const unsigned short* __restrict__ Bt,   // [N][K] bf16 bits
    void* __restrict__ Cp,                   // [M][N] bf16 bits or f32
    int M, int N, int K, float scale) {
  __shared__ __align__(16) unsigned short sA[BM * BK];
  __shared__ __align__(16) unsigned short sB[BN * BK];

  const int tid  = threadIdx.x;
  const int bm   = blockIdx.y * BM;
  const int bn   = blockIdx.x * BN;
  const int wave = tid >> 6;
  const int lane = tid & 63;
  const int q    = lane >> 4;
  const int l16  = lane & 15;
  const int wm   = (wave >> 1) * 64;
  const int wn   = (wave & 1) * 64;

  f32x4 zero = {0.f, 0.f, 0.f, 0.f};
  f32x4 acc[4][4];
#pragma unroll
  for (int t = 0; t < 4; t++)
#pragma unroll
    for (int u = 0; u < 4; u++) acc[t][u] = zero;

  // Staging map: thread t stages rows (t>>2) and (t>>2)+64, k-chunk (t&3)*8.
  // LDS linear layout == row-major [128][32], 16B per thread slot.
  const unsigned short* ap = A  + (size_t)(bm + (tid >> 2)) * K + (tid & 3) * 8;
  const unsigned short* bp = Bt + (size_t)(bn + (tid >> 2)) * K + (tid & 3) * 8;
  unsigned short* sa_dst = sA + tid * 8;
  unsigned short* sb_dst = sB + tid * 8;
  const size_t skip = (size_t)64 * K;

  for (int k0 = 0; k0 < K; k0 += BK) {
    u16x8 a0 = *(const u16x8*)(ap + k0);
    u16x8 a1 = *(const u16x8*)(ap + k0 + skip);
    u16x8 b0 = *(const u16x8*)(bp + k0);
    u16x8 b1 = *(const u16x8*)(bp + k0 + skip);
    *(u16x8*)(sa_dst)            = a0;
    *(u16x8*)(sa_dst + 64 * BK)  = a1;
    *(u16x8*)(sb_dst)            = b0;
    *(u16x8*)(sb_dst + 64 * BK)  = b1;
    __syncthreads();

    bf16x8 af[4], bfv[4];
#pragma unroll
    for (int t = 0; t < 4; t++)
      af[t] = *reinterpret_cast<const bf16x8*>(sA + (wm + t * 16 + l16) * BK + q * 8);
#pragma unroll
    for (int u = 0; u < 4; u++)
      bfv[u] = *reinterpret_cast<const bf16x8*>(sB + (wn + u * 16 + l16) * BK + q * 8);
#pragma unroll
    for (int t = 0; t < 4; t++)
#pragma unroll
      for (int u = 0; u < 4; u++)
        acc[t][u] = __builtin_amdgcn_mfma_f32_16x16x32_bf16(af[t], bfv[u], acc[t][u], 0, 0, 0);
    __syncthreads();
  }

#pragma unroll
  for (int t = 0; t < 4; t++) {
#pragma unroll
    for (int u = 0; u < 4; u++) {
      const int row0 = bm + wm + t * 16 + q * 4;
      const int col  = bn + wn + u * 16 + l16;
#pragma unroll
      for (int r = 0; r < 4; r++) {
        float v = acc[t][u][r] * scale;
        if constexpr (OUT_BF16)
          ((unsigned short*)Cp)[(size_t)(row0 + r) * N + col] = f2bf(v);
        else
          ((float*)Cp)[(size_t)(row0 + r) * N + col] = v;
      }
    }
  }
}

// ---------------- in-place row softmax over 4096 bf16 scores ----------------
__global__ __launch_bounds__(256) void softmax_rows_kernel(unsigned short* __restrict__ SP) {
  const int n = S_DIM;
  unsigned short* rp = SP + (size_t)blockIdx.x * n;
  const int tid = threadIdx.x;
  u16x8 c0 = *(const u16x8*)(rp + tid * 16);
  u16x8 c1 = *(const u16x8*)(rp + tid * 16 + 8);
  float v[16];
#pragma unroll
  for (int j = 0; j < 8; j++) { v[j] = bf2f(c0[j]); v[8 + j] = bf2f(c1[j]); }

  float m = v[0];
#pragma unroll
  for (int j = 1; j < 16; j++) m = fmaxf(m, v[j]);
#pragma unroll
  for (int o = 32; o > 0; o >>= 1) m = fmaxf(m, __shfl_xor(m, o));
  __shared__ float redm[4];
  __shared__ float reds[4];
  if ((tid & 63) == 0) redm[tid >> 6] = m;
  __syncthreads();
  m = fmaxf(fmaxf(redm[0], redm[1]), fmaxf(redm[2], redm[3]));

  float s = 0.f;
#pragma unroll
  for (int j = 0; j < 16; j++) { v[j] = __expf(v[j] - m); s += v[j]; }
#pragma unroll
  for (int o = 32; o > 0; o >>= 1) s += __shfl_xor(s, o);
  if ((tid & 63) == 0) reds[tid >> 6] = s;
  __syncthreads();
  s = (reds[0] + reds[1]) + (reds[2] + reds[3]);
  float inv = 1.0f / s;

#pragma unroll
  for (int j = 0; j < 8; j++) { c0[j] = f2bf(v[j] * inv); c1[j] = f2bf(v[8 + j] * inv); }
  *(u16x8*)(rp + tid * 16)     = c0;
  *(u16x8*)(rp + tid * 16 + 8) = c1;
}

extern "C" void kernel_launch(void* const* d_in, const int* in_sizes, int n_in,
                              void* d_out, int out_size, void* d_ws, size_t ws_size,
                              hipStream_t stream) {
  const float* x  = (const float*)d_in[0];
  const float* Wq = (const float*)d_in[1];
  const float* Wk = (const float*)d_in[2];
  const float* Wv = (const float*)d_in[3];
  float* out = (float*)d_out;

  // Workspace layout (56 MB total). xbf/Wt/Vbf live inside the SP region but are
  // dead before the S-GEMM writes SP.
  char* ws = (char*)d_ws;
  const size_t MB = 1024 * 1024;
  unsigned short* Qbf = (unsigned short*)(ws + 0 * MB);    // [S][D] bf16, 8MB
  unsigned short* Kbf = (unsigned short*)(ws + 8 * MB);    // [S][D] bf16, 8MB
  unsigned short* Vt  = (unsigned short*)(ws + 16 * MB);   // [D][S] bf16, 8MB
  unsigned short* SP  = (unsigned short*)(ws + 24 * MB);   // [S][S] bf16, 32MB
  unsigned short* xbf = (unsigned short*)(ws + 24 * MB);   // [S][E] bf16, 8MB (temp)
  unsigned short* Wt  = (unsigned short*)(ws + 32 * MB);   // [D][E] bf16, 2MB (temp, reused x3)
  unsigned short* Vbf = (unsigned short*)(ws + 34 * MB);   // [S][D] bf16, 8MB (temp)

  dim3 blk(256);

  // 1. x -> bf16
  cvt_f32_bf16_kernel<<<(S_DIM * E_DIM) / (256 * 8), blk, 0, stream>>>(x, xbf, S_DIM * E_DIM);

  // 2-4. for each W: transpose-cast W[E][D] -> Wt[D][E], then project
  dim3 tgrid(D_DIM / 32, E_DIM / 32);
  dim3 pgrid(D_DIM / BN, S_DIM / BM);   // (8, 32)
  transpose_to_bf16_kernel<float><<<tgrid, blk, 0, stream>>>(Wq, Wt, E_DIM, D_DIM);
  gemm_bt_kernel<true><<<pgrid, blk, 0, stream>>>(xbf, Wt, Qbf, S_DIM, D_DIM, E_DIM, 1.0f);
  transpose_to_bf16_kernel<float><<<tgrid, blk, 0, stream>>>(Wk, Wt, E_DIM, D_DIM);
  gemm_bt_kernel<true><<<pgrid, blk, 0, stream>>>(xbf, Wt, Kbf, S_DIM, D_DIM, E_DIM, 1.0f);
  transpose_to_bf16_kernel<float><<<tgrid, blk, 0, stream>>>(Wv, Wt, E_DIM, D_DIM);
  gemm_bt_kernel<true><<<pgrid, blk, 0, stream>>>(xbf, Wt, Vbf, S_DIM, D_DIM, E_DIM, 1.0f);

  // 5. V[S][D] -> Vt[D][S]
  dim3 vtgrid(D_DIM / 32, S_DIM / 32);
  transpose_to_bf16_kernel<unsigned short><<<vtgrid, blk, 0, stream>>>(Vbf, Vt, S_DIM, D_DIM);

  // 6. SP = (Q @ K^T) / sqrt(D), bf16
  dim3 sgrid(S_DIM / BN, S_DIM / BM);   // (32, 32)
  gemm_bt_kernel<true><<<sgrid, blk, 0, stream>>>(Qbf, Kbf, SP, S_DIM, S_DIM, E_DIM, 0.03125f);

  // 7. softmax rows in place
  softmax_rows_kernel<<<S_DIM, blk, 0, stream>>>(SP);

  // 8. out = P @ V  (A = SP [S][S], Bt = Vt [D][S])
  dim3 ogrid(D_DIM / BN, S_DIM / BM);   // (8, 32)
  gemm_bt_kernel<false><<<ogrid, blk, 0, stream>>>(SP, Vt, out, S_DIM, D_DIM, S_DIM, 1.0f);
}

// Round 2
// 241.727 us; speedup vs baseline: 1.2334x; 1.2334x over previous
//
#include <hip/hip_runtime.h>
#include <cstdint>

#define S_DIM 4096
#define E_DIM 1024
#define D_DIM 1024

typedef __bf16 bf16x8 __attribute__((ext_vector_type(8)));
typedef float  f32x4  __attribute__((ext_vector_type(4)));
typedef unsigned short u16x8 __attribute__((ext_vector_type(8)));

__device__ __forceinline__ unsigned short f2bf(float f) {
  unsigned u = __float_as_uint(f);
  unsigned r = (u + 0x7fffu + ((u >> 16) & 1u)) >> 16;   // RNE
  return (unsigned short)r;
}
__device__ __forceinline__ float bf2f(unsigned short b) {
  return __uint_as_float(((unsigned)b) << 16);
}
__device__ __forceinline__ unsigned short to_bf16_bits(float f) { return f2bf(f); }
__device__ __forceinline__ unsigned short to_bf16_bits(unsigned short s) { return s; }

// Async global->LDS DMA, 16B per lane. HW semantics (m104/m108): LDS dst is
// wave-uniform base + lane*16; all lanes must pass the same LDS base and their
// own global address. AS casts via uintptr_t (CK spelling: low 32 bits of a
// generic LDS pointer ARE the LDS offset on gfx9-lineage).
__device__ __forceinline__ void lds_copy16(const unsigned short* g, const unsigned short* l) {
  auto gp = reinterpret_cast<__attribute__((address_space(1))) unsigned int*>(
      reinterpret_cast<uintptr_t>(g));
  auto lp = reinterpret_cast<__attribute__((address_space(3))) unsigned int*>(
      reinterpret_cast<uintptr_t>(l));
  __builtin_amdgcn_global_load_lds(gp, lp, 16, 0, 0);
}

// ---------------- elementwise f32 -> bf16 ----------------
__global__ __launch_bounds__(256) void cvt_f32_bf16_kernel(
    const float* __restrict__ in, unsigned short* __restrict__ out, int n) {
  int i = (blockIdx.x * 256 + threadIdx.x) * 8;
  if (i >= n) return;
  float4 a = *(const float4*)(in + i);
  float4 b = *(const float4*)(in + i + 4);
  u16x8 o;
  o[0] = f2bf(a.x); o[1] = f2bf(a.y); o[2] = f2bf(a.z); o[3] = f2bf(a.w);
  o[4] = f2bf(b.x); o[5] = f2bf(b.y); o[6] = f2bf(b.z); o[7] = f2bf(b.w);
  *(u16x8*)(out + i) = o;
}

// ---------------- tiled transpose -> bf16: out[c][r] = in[r][c] ----------------
template <typename TIN>
__global__ __launch_bounds__(256) void transpose_to_bf16_kernel(
    const TIN* __restrict__ in, unsigned short* __restrict__ out, int ldin, int ldout) {
  __shared__ unsigned short tile[32][33];           // +1 pad breaks bank conflicts
  int bc = blockIdx.x * 32, br = blockIdx.y * 32;
  int tx = threadIdx.x & 31;
  int ty = threadIdx.x >> 5;                        // 0..7
#pragma unroll
  for (int i = 0; i < 32; i += 8)
    tile[ty + i][tx] = to_bf16_bits(in[(size_t)(br + ty + i) * ldin + bc + tx]);
  __syncthreads();
#pragma unroll
  for (int i = 0; i < 32; i += 8)
    out[(size_t)(bc + ty + i) * ldout + br + tx] = tile[tx][ty + i];
}

// ---------------- bf16 GEMM: C[M][N] = scale * A[M][K] @ Bt[N][K]^T ----------------
// 128xTBN tile, BK=32, 4 waves (2x2). m97 structure: global_load_lds width=16
// staging, 2-barrier K-loop. Verified MFMA layouts (m89/m91/m92):
// A-frag lane l -> A[m=l&15][k=(l>>4)*8+j]; B-frag lane l -> Bt[n=l&15][k=(l>>4)*8+j];
// C/D lane l reg r -> D[row=(l>>4)*4+r][col=l&15].
// SPLIT3: output cols [0,1024)->Cp, [1024,2048)->C1, [2048,3072)->C2 (fused QKV).
template <int TBN, bool OUT_BF16, bool SPLIT3>
__global__ __launch_bounds__(256, 2) void gemm_bt_kernel(
    const unsigned short* __restrict__ A, int lda,
    const unsigned short* __restrict__ Bt, int ldb,
    void* __restrict__ Cp, unsigned short* __restrict__ C1,
    unsigned short* __restrict__ C2, int ldc,
    int K, float scale) {
  constexpr int NU = TBN / 32;                       // u-tiles per wave
  __shared__ __align__(16) unsigned short sA[128 * 32];
  __shared__ __align__(16) unsigned short sB[TBN * 32];

  const int tid = threadIdx.x;

  // 8-high M-group swizzle for L2 tile reuse (gridDim.y % 8 == 0 for all our grids)
  int flat = blockIdx.y * gridDim.x + blockIdx.x;
  int numInG = 8 * gridDim.x;
  int g = flat / numInG;
  int r = flat - g * numInG;
  const int bm = (g * 8 + (r & 7)) * 128;
  const int bn = (r >> 3) * TBN;

  const int wave = tid >> 6;
  const int lane = tid & 63;
  const int q    = lane >> 4;
  const int l16  = lane & 15;
  const int wm   = (wave >> 1) * 64;
  const int wn   = (wave & 1) * (TBN / 2);

  f32x4 zero = {0.f, 0.f, 0.f, 0.f};
  f32x4 acc[4][NU];
#pragma unroll
  for (int t = 0; t < 4; t++)
#pragma unroll
    for (int u = 0; u < NU; u++) acc[t][u] = zero;

  // Staging map: thread t -> row t>>2 (and +64 for A / B when TBN==128),
  // k-chunk (t&3)*8. LDS slot = t*16B == wave_base + lane*16B (DMA pattern).
  const unsigned short* ap = A  + (size_t)(bm + (tid >> 2)) * lda + (tid & 3) * 8;
  const unsigned short* bp = Bt + (size_t)(bn + (tid >> 2)) * ldb + (tid & 3) * 8;
  unsigned short* saw = sA + wave * 512;             // wave-uniform LDS bases
  unsigned short* sbw = sB + wave * 512;
  const size_t skipA = (size_t)64 * lda;
  const size_t skipB = (size_t)64 * ldb;

  for (int k0 = 0; k0 < K; k0 += 32) {
    lds_copy16(ap + k0,         saw);
    lds_copy16(ap + k0 + skipA, saw + 2048);
    lds_copy16(bp + k0,         sbw);
    if constexpr (TBN == 128) lds_copy16(bp + k0 + skipB, sbw + 2048);
    __syncthreads();                                  // drains vmcnt (DMA) too

    bf16x8 af[4], bfv[NU];
#pragma unroll
    for (int t = 0; t < 4; t++)
      af[t] = *reinterpret_cast<const bf16x8*>(sA + (wm + t * 16 + l16) * 32 + q * 8);
#pragma unroll
    for (int u = 0; u < NU; u++)
      bfv[u] = *reinterpret_cast<const bf16x8*>(sB + (wn + u * 16 + l16) * 32 + q * 8);
#pragma unroll
    for (int t = 0; t < 4; t++)
#pragma unroll
      for (int u = 0; u < NU; u++)
        acc[t][u] = __builtin_amdgcn_mfma_f32_16x16x32_bf16(af[t], bfv[u], acc[t][u], 0, 0, 0);
    __syncthreads();
  }

  unsigned short* cb16 = (unsigned short*)Cp;
  int coloff = bn;
  if constexpr (SPLIT3) {
    int which = bn >> 10;
    cb16 = (which == 0) ? (unsigned short*)Cp : (which == 1 ? C1 : C2);
    coloff = bn & 1023;
  }
#pragma unroll
  for (int t = 0; t < 4; t++) {
#pragma unroll
    for (int u = 0; u < NU; u++) {
      const int row0 = bm + wm + t * 16 + q * 4;
      const int col  = coloff + wn + u * 16 + l16;
#pragma unroll
      for (int rr = 0; rr < 4; rr++) {
        float v = acc[t][u][rr] * scale;
        if constexpr (OUT_BF16)
          cb16[(size_t)(row0 + rr) * ldc + col] = f2bf(v);
        else
          ((float*)Cp)[(size_t)(row0 + rr) * ldc + col] = v;
      }
    }
  }
}

// ---------------- in-place row softmax over 4096 bf16 scores ----------------
__global__ __launch_bounds__(256) void softmax_rows_kernel(unsigned short* __restrict__ SP) {
  unsigned short* rp = SP + (size_t)blockIdx.x * S_DIM;
  const int tid = threadIdx.x;
  u16x8 c0 = *(const u16x8*)(rp + tid * 16);
  u16x8 c1 = *(const u16x8*)(rp + tid * 16 + 8);
  float v[16];
#pragma unroll
  for (int j = 0; j < 8; j++) { v[j] = bf2f(c0[j]); v[8 + j] = bf2f(c1[j]); }

  float m = v[0];
#pragma unroll
  for (int j = 1; j < 16; j++) m = fmaxf(m, v[j]);
#pragma unroll
  for (int o = 32; o > 0; o >>= 1) m = fmaxf(m, __shfl_xor(m, o));
  __shared__ float redm[4];
  __shared__ float reds[4];
  if ((tid & 63) == 0) redm[tid >> 6] = m;
  __syncthreads();
  m = fmaxf(fmaxf(redm[0], redm[1]), fmaxf(redm[2], redm[3]));

  float s = 0.f;
#pragma unroll
  for (int j = 0; j < 16; j++) { v[j] = __expf(v[j] - m); s += v[j]; }
#pragma unroll
  for (int o = 32; o > 0; o >>= 1) s += __shfl_xor(s, o);
  if ((tid & 63) == 0) reds[tid >> 6] = s;
  __syncthreads();
  s = (reds[0] + reds[1]) + (reds[2] + reds[3]);
  float inv = 1.0f / s;

#pragma unroll
  for (int j = 0; j < 8; j++) { c0[j] = f2bf(v[j] * inv); c1[j] = f2bf(v[8 + j] * inv); }
  *(u16x8*)(rp + tid * 16)     = c0;
  *(u16x8*)(rp + tid * 16 + 8) = c1;
}

extern "C" void kernel_launch(void* const* d_in, const int* in_sizes, int n_in,
                              void* d_out, int out_size, void* d_ws, size_t ws_size,
                              hipStream_t stream) {
  const float* x  = (const float*)d_in[0];
  const float* Wq = (const float*)d_in[1];
  const float* Wk = (const float*)d_in[2];
  const float* Wv = (const float*)d_in[3];
  float* out = (float*)d_out;

  // Workspace (56 MB total, proven safe in round 1):
  //   [0,32)MB   SP [S][S] bf16          (written step 6)
  //     overlay: [0,8) Vtmp, [8,16) xbf, [16,22) Wt_all — all dead before step 6
  //   [32,40)MB  Q [S][D] bf16
  //   [40,48)MB  K [S][D] bf16
  //   [48,56)MB  Vt [D][S] bf16
  char* ws = (char*)d_ws;
  const size_t MB = 1024 * 1024;
  unsigned short* SP   = (unsigned short*)(ws);
  unsigned short* Vtmp = (unsigned short*)(ws);
  unsigned short* xbf  = (unsigned short*)(ws + 8 * MB);
  unsigned short* Wt   = (unsigned short*)(ws + 16 * MB);   // [3072][1024]
  unsigned short* Qbf  = (unsigned short*)(ws + 32 * MB);
  unsigned short* Kbf  = (unsigned short*)(ws + 40 * MB);
  unsigned short* Vt   = (unsigned short*)(ws + 48 * MB);   // [1024][4096]

  dim3 blk(256);

  // 1. x -> bf16
  cvt_f32_bf16_kernel<<<(S_DIM * E_DIM) / (256 * 8), blk, 0, stream>>>(x, xbf, S_DIM * E_DIM);

  // 2. W transposes into stacked Wt_all [3][1024][1024]
  dim3 tgrid(32, 32);
  transpose_to_bf16_kernel<float><<<tgrid, blk, 0, stream>>>(Wq, Wt,                 D_DIM, E_DIM);
  transpose_to_bf16_kernel<float><<<tgrid, blk, 0, stream>>>(Wk, Wt + 1024 * 1024,   D_DIM, E_DIM);
  transpose_to_bf16_kernel<float><<<tgrid, blk, 0, stream>>>(Wv, Wt + 2 * 1024 * 1024, D_DIM, E_DIM);

  // 3. fused QKV projection: [4096][3072] split to Q, K, Vtmp
  dim3 pgrid(3072 / 128, S_DIM / 128);   // (24, 32) = 768 blocks
  gemm_bt_kernel<128, true, true><<<pgrid, blk, 0, stream>>>(
      xbf, E_DIM, Wt, E_DIM, Qbf, Kbf, Vtmp, D_DIM, E_DIM, 1.0f);

  // 4. Vtmp [S][D] -> Vt [D][S]
  dim3 vtgrid(D_DIM / 32, S_DIM / 32);   // (32, 128)
  transpose_to_bf16_kernel<unsigned short><<<vtgrid, blk, 0, stream>>>(Vtmp, Vt, D_DIM, S_DIM);

  // 5. SP = (Q @ K^T) / 32
  dim3 sgrid(S_DIM / 128, S_DIM / 128);  // (32, 32) = 1024 blocks
  gemm_bt_kernel<128, true, false><<<sgrid, blk, 0, stream>>>(
      Qbf, D_DIM, Kbf, D_DIM, SP, nullptr, nullptr, S_DIM, D_DIM, 0.03125f);

  // 6. softmax rows in place
  softmax_rows_kernel<<<S_DIM, blk, 0, stream>>>(SP);

  // 7. out = P @ V   (A = SP [S][S], Bt = Vt [D][S]); BN=64 -> 512 blocks
  dim3 ogrid(D_DIM / 64, S_DIM / 128);   // (16, 32)
  gemm_bt_kernel<64, false, false><<<ogrid, blk, 0, stream>>>(
      SP, S_DIM, Vt, S_DIM, out, nullptr, nullptr, D_DIM, S_DIM, 1.0f);
}